// Round 1
// baseline (1090.289 us; speedup 1.0000x reference)
//
#include <hip/hip_runtime.h>

#define BB 4
#define CC 256
#define NN 4096
#define GG 8

typedef unsigned short u16;
typedef unsigned int u32;
typedef __bf16 b16x8 __attribute__((ext_vector_type(8)));
typedef float f32x4 __attribute__((ext_vector_type(4)));
typedef u32 u32x4 __attribute__((ext_vector_type(4)));
typedef u16 u16x4 __attribute__((ext_vector_type(4)));

// Q pre-scale: C^-0.5 * log2(e) so softmax runs in exp2 domain
#define QSCALE 0.09016844005556021f

__device__ __forceinline__ u16 f2bf(float f) {
    u32 u = __builtin_bit_cast(u32, f);
    u = (u + 0x7FFFu + ((u >> 16) & 1u)) >> 16;
    return (u16)u;
}

__device__ __forceinline__ b16x8 ldfrag(const u16* p) {
    u32x4 v = *reinterpret_cast<const u32x4*>(p);
    return __builtin_bit_cast(b16x8, v);
}

// ---------------- 1. GroupNorm stats: one block per (b,g) ----------------
__global__ void gn_stats(const float* __restrict__ x, float* __restrict__ stats) {
    int bg = blockIdx.x;                       // 0..31
    const float4* p4 = (const float4*)(x + (size_t)bg * (CC / GG) * NN);
    const int total4 = (CC / GG) * NN / 4;     // 32768
    float s = 0.f, ss = 0.f;
    for (int i = threadIdx.x; i < total4; i += 256) {
        float4 v = p4[i];
        s  += v.x + v.y + v.z + v.w;
        ss += v.x * v.x + v.y * v.y + v.z * v.z + v.w * v.w;
    }
    #pragma unroll
    for (int off = 32; off; off >>= 1) {
        s  += __shfl_down(s, off, 64);
        ss += __shfl_down(ss, off, 64);
    }
    __shared__ float rs[4], rss[4];
    int wid = threadIdx.x >> 6;
    if ((threadIdx.x & 63) == 0) { rs[wid] = s; rss[wid] = ss; }
    __syncthreads();
    if (threadIdx.x == 0) {
        s  = rs[0] + rs[1] + rs[2] + rs[3];
        ss = rss[0] + rss[1] + rss[2] + rss[3];
        const float inv = 1.f / ((CC / GG) * NN);
        float mu = s * inv;
        float var = ss * inv - mu * mu;
        stats[bg * 2]     = mu;
        stats[bg * 2 + 1] = rsqrtf(var + 1e-5f);
    }
}

// ------- 2. Fold GN into QKV weights (per batch) + bf16 w_proj -------
__global__ void fold_w(const float* __restrict__ w_qkv, const float* __restrict__ w_proj,
                       const float* __restrict__ gamma, const float* __restrict__ beta,
                       const float* __restrict__ stats,
                       u16* __restrict__ wq_bf, float* __restrict__ biasq,
                       u16* __restrict__ wp_bf) {
    int o = blockIdx.x;        // 0..767
    int b = blockIdx.y;        // 0..3
    int c = threadIdx.x;       // 0..255
    int g = c >> 5;
    float mu   = stats[(b * GG + g) * 2];
    float rstd = stats[(b * GG + g) * 2 + 1];
    float a  = gamma[c] * rstd;
    float bb = beta[c] - mu * a;
    float w = w_qkv[o * CC + c];
    wq_bf[((size_t)b * 768 + o) * CC + c] = f2bf(w * a);
    float part = w * bb;
    #pragma unroll
    for (int off = 32; off; off >>= 1) part += __shfl_down(part, off, 64);
    __shared__ float red[4];
    if ((threadIdx.x & 63) == 0) red[threadIdx.x >> 6] = part;
    __syncthreads();
    if (threadIdx.x == 0) biasq[b * 768 + o] = red[0] + red[1] + red[2] + red[3];
    if (b == 0 && o < CC) wp_bf[o * CC + c] = f2bf(w_proj[o * CC + c]);
}

// ---------------- 3. x [B][C][N] fp32 -> XT [B][N][C] bf16 ----------------
__global__ void transpose_x(const float* __restrict__ x, u16* __restrict__ xt) {
    __shared__ float tile[64][65];
    int n0 = blockIdx.x * 64, c0 = blockIdx.y * 64, b = blockIdx.z;
    int t = threadIdx.x;
    int col = t & 63, r0 = t >> 6;
    const float* xp = x + (size_t)b * CC * NN;
    #pragma unroll
    for (int i = 0; i < 16; ++i) {
        int row = i * 4 + r0;
        tile[row][col] = xp[(size_t)(c0 + row) * NN + n0 + col];
    }
    __syncthreads();
    int nl = t >> 2;               // 0..63
    int cb = (t & 3) * 16;         // 0,16,32,48
    u16* op = xt + ((size_t)b * NN + n0 + nl) * CC + c0 + cb;
    #pragma unroll
    for (int j = 0; j < 16; j += 4) {
        u16x4 v;
        v.x = f2bf(tile[cb + j + 0][nl]);
        v.y = f2bf(tile[cb + j + 1][nl]);
        v.z = f2bf(tile[cb + j + 2][nl]);
        v.w = f2bf(tile[cb + j + 3][nl]);
        *reinterpret_cast<u16x4*>(op + j) = v;
    }
}

// ------- 4. QKV GEMM: [768x256]x[256x4096] per batch -> QT,KT [N][C], V [C][N] -------
__global__ void __launch_bounds__(256) qkv_gemm(const u16* __restrict__ wq_bf,
                                                const float* __restrict__ biasq,
                                                const u16* __restrict__ xt,
                                                u16* __restrict__ qt, u16* __restrict__ kt,
                                                u16* __restrict__ vv) {
    int b = blockIdx.z;
    int o0 = blockIdx.y * 64;
    int n0 = blockIdx.x * 64;
    int lane = threadIdx.x & 63, w = threadIdx.x >> 6;
    int l15 = lane & 15, quad = lane >> 4;
    const u16* A  = wq_bf + ((size_t)b * 768 + o0 + w * 16 + l15) * CC + quad * 8;
    const u16* Bp = xt + ((size_t)b * NN + n0 + l15) * CC + quad * 8;
    f32x4 acc[4] = {};
    #pragma unroll
    for (int kk = 0; kk < 8; ++kk) {
        b16x8 af = ldfrag(A + kk * 32);
        #pragma unroll
        for (int nt = 0; nt < 4; ++nt) {
            b16x8 bf = ldfrag(Bp + (size_t)nt * 16 * CC + kk * 32);
            acc[nt] = __builtin_amdgcn_mfma_f32_16x16x32_bf16(af, bf, acc[nt], 0, 0, 0);
        }
    }
    int o_base = o0 + w * 16 + quad * 4;
    float bias[4];
    #pragma unroll
    for (int r = 0; r < 4; ++r) bias[r] = biasq[b * 768 + o_base + r];
    #pragma unroll
    for (int nt = 0; nt < 4; ++nt) {
        int n = n0 + nt * 16 + l15;
        if (o0 < 256) {
            u16x4 pk;
            pk.x = f2bf((acc[nt][0] + bias[0]) * QSCALE);
            pk.y = f2bf((acc[nt][1] + bias[1]) * QSCALE);
            pk.z = f2bf((acc[nt][2] + bias[2]) * QSCALE);
            pk.w = f2bf((acc[nt][3] + bias[3]) * QSCALE);
            *reinterpret_cast<u16x4*>(qt + ((size_t)b * NN + n) * CC + o_base) = pk;
        } else if (o0 < 512) {
            u16x4 pk;
            pk.x = f2bf(acc[nt][0] + bias[0]);
            pk.y = f2bf(acc[nt][1] + bias[1]);
            pk.z = f2bf(acc[nt][2] + bias[2]);
            pk.w = f2bf(acc[nt][3] + bias[3]);
            *reinterpret_cast<u16x4*>(kt + ((size_t)b * NN + n) * CC + (o_base - 256)) = pk;
        } else {
            #pragma unroll
            for (int r = 0; r < 4; ++r)
                vv[((size_t)b * CC + (o_base - 512 + r)) * NN + n] = f2bf(acc[nt][r] + bias[r]);
        }
    }
}

// ---------------- 5. Flash attention: 64 Q rows per block ----------------
__global__ void __launch_bounds__(256, 2) flash(const u16* __restrict__ qt,
                                                const u16* __restrict__ kt,
                                                const u16* __restrict__ vv,
                                                u16* __restrict__ ot) {
    int b = blockIdx.y;
    int n0 = blockIdx.x * 64;
    int lane = threadIdx.x & 63, w = threadIdx.x >> 6;
    int l15 = lane & 15, quad = lane >> 4;
    __shared__ u16 plds[4][16 * 80];           // per-wave P tile, stride 80 for 16B-aligned reads
    u16* pl = &plds[w][0];

    // Q fragments held in registers for the whole block
    const u16* Qp = qt + ((size_t)b * NN + n0 + w * 16 + l15) * CC + quad * 8;
    b16x8 aq[8];
    #pragma unroll
    for (int kk = 0; kk < 8; ++kk) aq[kk] = ldfrag(Qp + kk * 32);

    f32x4 acco[16] = {};
    float m_r[4], l_r[4];
    #pragma unroll
    for (int r = 0; r < 4; ++r) { m_r[r] = -3.0e38f; l_r[r] = 0.f; }

    for (int m0 = 0; m0 < NN; m0 += 64) {
        // S = Q^T K  (already includes C^-0.5*log2e via Q pre-scale)
        f32x4 accs[4] = {};
        const u16* Kp = kt + ((size_t)b * NN + m0 + l15) * CC + quad * 8;
        #pragma unroll
        for (int kk = 0; kk < 8; ++kk) {
            #pragma unroll
            for (int mt = 0; mt < 4; ++mt) {
                b16x8 bk = ldfrag(Kp + (size_t)mt * 16 * CC + kk * 32);
                accs[mt] = __builtin_amdgcn_mfma_f32_16x16x32_bf16(aq[kk], bk, accs[mt], 0, 0, 0);
            }
        }
        // online softmax (exp2 domain), rows r = quad*4+reg
        float mx[4];
        #pragma unroll
        for (int r = 0; r < 4; ++r)
            mx[r] = fmaxf(fmaxf(accs[0][r], accs[1][r]), fmaxf(accs[2][r], accs[3][r]));
        #pragma unroll
        for (int off = 1; off < 16; off <<= 1) {
            #pragma unroll
            for (int r = 0; r < 4; ++r) mx[r] = fmaxf(mx[r], __shfl_xor(mx[r], off, 64));
        }
        float alpha[4];
        #pragma unroll
        for (int r = 0; r < 4; ++r) {
            float mn = fmaxf(m_r[r], mx[r]);
            alpha[r] = exp2f(m_r[r] - mn);
            m_r[r] = mn;
        }
        float rs[4];
        #pragma unroll
        for (int mt = 0; mt < 4; ++mt) {
            #pragma unroll
            for (int r = 0; r < 4; ++r) accs[mt][r] = exp2f(accs[mt][r] - m_r[r]);
        }
        #pragma unroll
        for (int r = 0; r < 4; ++r)
            rs[r] = accs[0][r] + accs[1][r] + accs[2][r] + accs[3][r];
        #pragma unroll
        for (int off = 1; off < 16; off <<= 1) {
            #pragma unroll
            for (int r = 0; r < 4; ++r) rs[r] += __shfl_xor(rs[r], off, 64);
        }
        #pragma unroll
        for (int r = 0; r < 4; ++r) l_r[r] = l_r[r] * alpha[r] + rs[r];
        #pragma unroll
        for (int ct = 0; ct < 16; ++ct) {
            #pragma unroll
            for (int r = 0; r < 4; ++r) acco[ct][r] *= alpha[r];
        }
        // P (C/D layout) -> LDS -> A-operand layout
        #pragma unroll
        for (int mt = 0; mt < 4; ++mt) {
            #pragma unroll
            for (int r = 0; r < 4; ++r)
                pl[(quad * 4 + r) * 80 + mt * 16 + l15] = f2bf(accs[mt][r]);
        }
        __asm__ volatile("s_waitcnt lgkmcnt(0)" ::: "memory");
        // O^T += P V^T
        const u16* Vp = vv + ((size_t)b * CC + l15) * NN + m0 + quad * 8;
        #pragma unroll
        for (int ks = 0; ks < 2; ++ks) {
            b16x8 ap = ldfrag(pl + l15 * 80 + ks * 32 + quad * 8);
            #pragma unroll
            for (int ct = 0; ct < 16; ++ct) {
                b16x8 bv = ldfrag(Vp + (size_t)ct * 16 * NN + ks * 32);
                acco[ct] = __builtin_amdgcn_mfma_f32_16x16x32_bf16(ap, bv, acco[ct], 0, 0, 0);
            }
        }
    }
    // epilogue: O /= l, write OT [B][N][C] bf16
    float inv_l[4];
    #pragma unroll
    for (int r = 0; r < 4; ++r) inv_l[r] = 1.f / l_r[r];
    u16* Op = ot + ((size_t)b * NN + n0 + w * 16) * CC;
    #pragma unroll
    for (int ct = 0; ct < 16; ++ct) {
        #pragma unroll
        for (int r = 0; r < 4; ++r)
            Op[(size_t)(quad * 4 + r) * CC + ct * 16 + l15] = f2bf(acco[ct][r] * inv_l[r]);
    }
}

// ------- 6. proj GEMM + bias + residual: out = x + W_p O + b_p -------
__global__ void __launch_bounds__(256) proj(const u16* __restrict__ wp_bf,
                                            const float* __restrict__ b_proj,
                                            const u16* __restrict__ ot,
                                            const float* __restrict__ x,
                                            float* __restrict__ out) {
    int b = blockIdx.z, o0 = blockIdx.y * 64, n0 = blockIdx.x * 64;
    int lane = threadIdx.x & 63, w = threadIdx.x >> 6;
    int l15 = lane & 15, quad = lane >> 4;
    const u16* A  = wp_bf + (size_t)(o0 + w * 16 + l15) * CC + quad * 8;
    const u16* Bp = ot + ((size_t)b * NN + n0 + l15) * CC + quad * 8;
    f32x4 acc[4] = {};
    #pragma unroll
    for (int kk = 0; kk < 8; ++kk) {
        b16x8 af = ldfrag(A + kk * 32);
        #pragma unroll
        for (int nt = 0; nt < 4; ++nt) {
            b16x8 bf = ldfrag(Bp + (size_t)nt * 16 * CC + kk * 32);
            acc[nt] = __builtin_amdgcn_mfma_f32_16x16x32_bf16(af, bf, acc[nt], 0, 0, 0);
        }
    }
    int o_base = o0 + w * 16 + quad * 4;
    #pragma unroll
    for (int nt = 0; nt < 4; ++nt) {
        int n = n0 + nt * 16 + l15;
        #pragma unroll
        for (int r = 0; r < 4; ++r) {
            int o = o_base + r;
            size_t idx = ((size_t)(b * CC + o)) * NN + n;
            out[idx] = acc[nt][r] + b_proj[o] + x[idx];
        }
    }
}

extern "C" void kernel_launch(void* const* d_in, const int* in_sizes, int n_in,
                              void* d_out, int out_size, void* d_ws, size_t ws_size,
                              hipStream_t stream) {
    const float* x      = (const float*)d_in[0];
    const float* gamma  = (const float*)d_in[1];
    const float* beta   = (const float*)d_in[2];
    const float* w_qkv  = (const float*)d_in[3];
    const float* w_proj = (const float*)d_in[4];
    const float* b_proj = (const float*)d_in[5];
    float* out = (float*)d_out;

    char* p = (char*)d_ws;
    float* stats = (float*)p; p += 256;
    float* biasq = (float*)p; p += (size_t)BB * 768 * sizeof(float);
    u16* wq_bf = (u16*)p; p += (size_t)BB * 768 * CC * 2;
    u16* wp_bf = (u16*)p; p += (size_t)CC * CC * 2;
    u16* xt = (u16*)p; p += (size_t)BB * NN * CC * 2;
    u16* qt = (u16*)p; p += (size_t)BB * NN * CC * 2;
    u16* kt = (u16*)p; p += (size_t)BB * NN * CC * 2;
    u16* vv = (u16*)p; p += (size_t)BB * NN * CC * 2;
    u16* ot = (u16*)p; p += (size_t)BB * NN * CC * 2;
    (void)ws_size; (void)in_sizes; (void)n_in; (void)out_size;

    gn_stats<<<BB * GG, 256, 0, stream>>>(x, stats);
    fold_w<<<dim3(768, BB), 256, 0, stream>>>(w_qkv, w_proj, gamma, beta, stats, wq_bf, biasq, wp_bf);
    transpose_x<<<dim3(NN / 64, CC / 64, BB), 256, 0, stream>>>(x, xt);
    qkv_gemm<<<dim3(NN / 64, 12, BB), 256, 0, stream>>>(wq_bf, biasq, xt, qt, kt, vv);
    flash<<<dim3(NN / 64, BB), 256, 0, stream>>>(qt, kt, vv, ot);
    proj<<<dim3(NN / 64, CC / 64, BB), 256, 0, stream>>>(wp_bf, b_proj, ot, x, out);
}

// Round 2
// 723.209 us; speedup vs baseline: 1.5076x; 1.5076x over previous
//
#include <hip/hip_runtime.h>

#define BB 4
#define CC 256
#define NN 4096
#define GG 8
#define SPLITS 4
#define KVPER (NN / SPLITS)

typedef unsigned short u16;
typedef unsigned int u32;
typedef __bf16 b16x8 __attribute__((ext_vector_type(8)));
typedef float f32x4 __attribute__((ext_vector_type(4)));
typedef u32 u32x4 __attribute__((ext_vector_type(4)));
typedef u16 u16x4 __attribute__((ext_vector_type(4)));

// Q pre-scale: C^-0.5 * log2(e) so softmax runs in exp2 domain
#define QSCALE 0.09016844005556021f
// Fixed softmax "max" (exp2 domain). Realistic score max ~ +9; fp32 exp2 is
// finite to 2^127, so no overflow risk and relative precision is scale-free.
#define FMAX 16.0f

__device__ __forceinline__ u16 f2bf(float f) {
    u32 u = __builtin_bit_cast(u32, f);
    u = (u + 0x7FFFu + ((u >> 16) & 1u)) >> 16;
    return (u16)u;
}

__device__ __forceinline__ float bf2f(u16 h) {
    return __builtin_bit_cast(float, (u32)h << 16);
}

__device__ __forceinline__ b16x8 ldfrag(const u16* p) {
    u32x4 v = *reinterpret_cast<const u32x4*>(p);
    return __builtin_bit_cast(b16x8, v);
}

// ---------------- 1. GroupNorm stats: one block per (b,g) ----------------
__global__ void gn_stats(const float* __restrict__ x, float* __restrict__ stats) {
    int bg = blockIdx.x;                       // 0..31
    const float4* p4 = (const float4*)(x + (size_t)bg * (CC / GG) * NN);
    const int total4 = (CC / GG) * NN / 4;     // 32768
    float s = 0.f, ss = 0.f;
    for (int i = threadIdx.x; i < total4; i += 256) {
        float4 v = p4[i];
        s  += v.x + v.y + v.z + v.w;
        ss += v.x * v.x + v.y * v.y + v.z * v.z + v.w * v.w;
    }
    #pragma unroll
    for (int off = 32; off; off >>= 1) {
        s  += __shfl_down(s, off, 64);
        ss += __shfl_down(ss, off, 64);
    }
    __shared__ float rs[4], rss[4];
    int wid = threadIdx.x >> 6;
    if ((threadIdx.x & 63) == 0) { rs[wid] = s; rss[wid] = ss; }
    __syncthreads();
    if (threadIdx.x == 0) {
        s  = rs[0] + rs[1] + rs[2] + rs[3];
        ss = rss[0] + rss[1] + rss[2] + rss[3];
        const float inv = 1.f / ((CC / GG) * NN);
        float mu = s * inv;
        float var = ss * inv - mu * mu;
        stats[bg * 2]     = mu;
        stats[bg * 2 + 1] = rsqrtf(var + 1e-5f);
    }
}

// ------- 2. Fold GN into QKV weights (per batch) + bf16 w_proj -------
__global__ void fold_w(const float* __restrict__ w_qkv, const float* __restrict__ w_proj,
                       const float* __restrict__ gamma, const float* __restrict__ beta,
                       const float* __restrict__ stats,
                       u16* __restrict__ wq_bf, float* __restrict__ biasq,
                       u16* __restrict__ wp_bf) {
    int o = blockIdx.x;        // 0..767
    int b = blockIdx.y;        // 0..3
    int c = threadIdx.x;       // 0..255
    int g = c >> 5;
    float mu   = stats[(b * GG + g) * 2];
    float rstd = stats[(b * GG + g) * 2 + 1];
    float a  = gamma[c] * rstd;
    float bb = beta[c] - mu * a;
    float w = w_qkv[o * CC + c];
    wq_bf[((size_t)b * 768 + o) * CC + c] = f2bf(w * a);
    float part = w * bb;
    #pragma unroll
    for (int off = 32; off; off >>= 1) part += __shfl_down(part, off, 64);
    __shared__ float red[4];
    if ((threadIdx.x & 63) == 0) red[threadIdx.x >> 6] = part;
    __syncthreads();
    if (threadIdx.x == 0) biasq[b * 768 + o] = red[0] + red[1] + red[2] + red[3];
    if (b == 0 && o < CC) wp_bf[o * CC + c] = f2bf(w_proj[o * CC + c]);
}

// ---------------- 3. x [B][C][N] fp32 -> XT [B][N][C] bf16 ----------------
__global__ void transpose_x(const float* __restrict__ x, u16* __restrict__ xt) {
    __shared__ float tile[64][65];
    int n0 = blockIdx.x * 64, c0 = blockIdx.y * 64, b = blockIdx.z;
    int t = threadIdx.x;
    int col = t & 63, r0 = t >> 6;
    const float* xp = x + (size_t)b * CC * NN;
    #pragma unroll
    for (int i = 0; i < 16; ++i) {
        int row = i * 4 + r0;
        tile[row][col] = xp[(size_t)(c0 + row) * NN + n0 + col];
    }
    __syncthreads();
    int nl = t >> 2;               // 0..63
    int cb = (t & 3) * 16;         // 0,16,32,48
    u16* op = xt + ((size_t)b * NN + n0 + nl) * CC + c0 + cb;
    #pragma unroll
    for (int j = 0; j < 16; j += 4) {
        u16x4 v;
        v.x = f2bf(tile[cb + j + 0][nl]);
        v.y = f2bf(tile[cb + j + 1][nl]);
        v.z = f2bf(tile[cb + j + 2][nl]);
        v.w = f2bf(tile[cb + j + 3][nl]);
        *reinterpret_cast<u16x4*>(op + j) = v;
    }
}

// ------- 4. QKV GEMM: [768x256]x[256x4096] per batch -> QT,KT [N][C], V [C][N] -------
__global__ void __launch_bounds__(256) qkv_gemm(const u16* __restrict__ wq_bf,
                                                const float* __restrict__ biasq,
                                                const u16* __restrict__ xt,
                                                u16* __restrict__ qt, u16* __restrict__ kt,
                                                u16* __restrict__ vv) {
    int b = blockIdx.z;
    int o0 = blockIdx.y * 64;
    int n0 = blockIdx.x * 64;
    int lane = threadIdx.x & 63, w = threadIdx.x >> 6;
    int l15 = lane & 15, quad = lane >> 4;
    const u16* A  = wq_bf + ((size_t)b * 768 + o0 + w * 16 + l15) * CC + quad * 8;
    const u16* Bp = xt + ((size_t)b * NN + n0 + l15) * CC + quad * 8;
    f32x4 acc[4] = {};
    #pragma unroll
    for (int kk = 0; kk < 8; ++kk) {
        b16x8 af = ldfrag(A + kk * 32);
        #pragma unroll
        for (int nt = 0; nt < 4; ++nt) {
            b16x8 bf = ldfrag(Bp + (size_t)nt * 16 * CC + kk * 32);
            acc[nt] = __builtin_amdgcn_mfma_f32_16x16x32_bf16(af, bf, acc[nt], 0, 0, 0);
        }
    }
    int o_base = o0 + w * 16 + quad * 4;
    float bias[4];
    #pragma unroll
    for (int r = 0; r < 4; ++r) bias[r] = biasq[b * 768 + o_base + r];
    #pragma unroll
    for (int nt = 0; nt < 4; ++nt) {
        int n = n0 + nt * 16 + l15;
        if (o0 < 256) {
            u16x4 pk;
            pk.x = f2bf((acc[nt][0] + bias[0]) * QSCALE);
            pk.y = f2bf((acc[nt][1] + bias[1]) * QSCALE);
            pk.z = f2bf((acc[nt][2] + bias[2]) * QSCALE);
            pk.w = f2bf((acc[nt][3] + bias[3]) * QSCALE);
            *reinterpret_cast<u16x4*>(qt + ((size_t)b * NN + n) * CC + o_base) = pk;
        } else if (o0 < 512) {
            u16x4 pk;
            pk.x = f2bf(acc[nt][0] + bias[0]);
            pk.y = f2bf(acc[nt][1] + bias[1]);
            pk.z = f2bf(acc[nt][2] + bias[2]);
            pk.w = f2bf(acc[nt][3] + bias[3]);
            *reinterpret_cast<u16x4*>(kt + ((size_t)b * NN + n) * CC + (o_base - 256)) = pk;
        } else {
            #pragma unroll
            for (int r = 0; r < 4; ++r)
                vv[((size_t)b * CC + (o_base - 512 + r)) * NN + n] = f2bf(acc[nt][r] + bias[r]);
        }
    }
}

// ---------------- 5. Flash attention, split-KV, fixed-max softmax ----------------
// grid (NN/64, SPLITS, BB); block 256. Writes unnormalized partial O (bf16)
// and partial l (fp32); combine kernel merges the SPLITS chunks.
__global__ void __launch_bounds__(256, 4) flash(const u16* __restrict__ qt,
                                                const u16* __restrict__ kt,
                                                const u16* __restrict__ vv,
                                                u16* __restrict__ po,
                                                float* __restrict__ lp) {
    int b = blockIdx.z;
    int sp = blockIdx.y;
    int n0 = blockIdx.x * 64;
    int lane = threadIdx.x & 63, w = threadIdx.x >> 6;
    int l15 = lane & 15, quad = lane >> 4;
    __shared__ u16 plds[4][16 * 80];           // per-wave P tile, stride 80
    u16* pl = &plds[w][0];

    // Q fragments held in registers for the whole block
    const u16* Qp = qt + ((size_t)b * NN + n0 + w * 16 + l15) * CC + quad * 8;
    b16x8 aq[8];
    #pragma unroll
    for (int kk = 0; kk < 8; ++kk) aq[kk] = ldfrag(Qp + kk * 32);

    f32x4 acco[16] = {};
    float l_r[4] = {0.f, 0.f, 0.f, 0.f};

    const int m_beg = sp * KVPER;
    for (int m0 = m_beg; m0 < m_beg + KVPER; m0 += 64) {
        // S = Q^T K  (C^-0.5*log2e pre-folded into Q)
        f32x4 accs[4] = {};
        const u16* Kp = kt + ((size_t)b * NN + m0 + l15) * CC + quad * 8;
        #pragma unroll
        for (int kk = 0; kk < 8; ++kk) {
            #pragma unroll
            for (int mt = 0; mt < 4; ++mt) {
                b16x8 bk = ldfrag(Kp + (size_t)mt * 16 * CC + kk * 32);
                accs[mt] = __builtin_amdgcn_mfma_f32_16x16x32_bf16(aq[kk], bk, accs[mt], 0, 0, 0);
            }
        }
        // p = exp2(s - FMAX); accumulate per-lane l partials (reduced at end)
        #pragma unroll
        for (int mt = 0; mt < 4; ++mt) {
            #pragma unroll
            for (int r = 0; r < 4; ++r) accs[mt][r] = exp2f(accs[mt][r] - FMAX);
        }
        #pragma unroll
        for (int r = 0; r < 4; ++r)
            l_r[r] += accs[0][r] + accs[1][r] + accs[2][r] + accs[3][r];
        // P (C/D layout) -> LDS -> A-operand layout
        #pragma unroll
        for (int mt = 0; mt < 4; ++mt) {
            #pragma unroll
            for (int r = 0; r < 4; ++r)
                pl[(quad * 4 + r) * 80 + mt * 16 + l15] = f2bf(accs[mt][r]);
        }
        __asm__ volatile("s_waitcnt lgkmcnt(0)" ::: "memory");
        // O^T += P V^T
        const u16* Vp = vv + ((size_t)b * CC + l15) * NN + m0 + quad * 8;
        #pragma unroll
        for (int ks = 0; ks < 2; ++ks) {
            b16x8 ap = ldfrag(pl + l15 * 80 + ks * 32 + quad * 8);
            #pragma unroll
            for (int ct = 0; ct < 16; ++ct) {
                b16x8 bv = ldfrag(Vp + (size_t)ct * 16 * NN + ks * 32);
                acco[ct] = __builtin_amdgcn_mfma_f32_16x16x32_bf16(ap, bv, acco[ct], 0, 0, 0);
            }
        }
    }
    // reduce l across the 16 lanes of each row group (same quad)
    #pragma unroll
    for (int off = 1; off < 16; off <<= 1) {
        #pragma unroll
        for (int r = 0; r < 4; ++r) l_r[r] += __shfl_xor(l_r[r], off, 64);
    }
    size_t obase = ((size_t)(sp * BB + b) * NN + n0 + w * 16);
    u16* Op = po + obase * CC;
    #pragma unroll
    for (int ct = 0; ct < 16; ++ct) {
        #pragma unroll
        for (int r = 0; r < 4; ++r)
            Op[(size_t)(quad * 4 + r) * CC + ct * 16 + l15] = f2bf(acco[ct][r]);
    }
    if (l15 == 0) {
        #pragma unroll
        for (int r = 0; r < 4; ++r) lp[obase + quad * 4 + r] = l_r[r];
    }
}

// ---------------- 5b. combine: ot = (sum_s po_s) / (sum_s l_s) ----------------
__global__ void __launch_bounds__(256) combine(const u16* __restrict__ po,
                                               const float* __restrict__ lp,
                                               u16* __restrict__ ot) {
    int idx = blockIdx.x * 256 + threadIdx.x;      // BB*NN*CC/8 threads
    int bn = idx >> 5;                             // row index in [0, BB*NN)
    int c8 = (idx & 31) * 8;
    float acc[8] = {};
    float lsum = 0.f;
    #pragma unroll
    for (int s = 0; s < SPLITS; ++s) {
        lsum += lp[(size_t)s * BB * NN + bn];
        u32x4 v = *reinterpret_cast<const u32x4*>(po + (((size_t)s * BB * NN + bn) * CC + c8));
        const u16* pv = reinterpret_cast<const u16*>(&v);
        #pragma unroll
        for (int j = 0; j < 8; ++j) acc[j] += bf2f(pv[j]);
    }
    float inv = 1.f / lsum;
    u16 outv[8];
    #pragma unroll
    for (int j = 0; j < 8; ++j) outv[j] = f2bf(acc[j] * inv);
    *reinterpret_cast<u32x4*>(ot + (size_t)bn * CC + c8) =
        *reinterpret_cast<const u32x4*>(outv);
}

// ------- 6. proj GEMM + bias + residual: out = x + W_p O + b_p -------
__global__ void __launch_bounds__(256) proj(const u16* __restrict__ wp_bf,
                                            const float* __restrict__ b_proj,
                                            const u16* __restrict__ ot,
                                            const float* __restrict__ x,
                                            float* __restrict__ out) {
    int b = blockIdx.z, o0 = blockIdx.y * 64, n0 = blockIdx.x * 64;
    int lane = threadIdx.x & 63, w = threadIdx.x >> 6;
    int l15 = lane & 15, quad = lane >> 4;
    const u16* A  = wp_bf + (size_t)(o0 + w * 16 + l15) * CC + quad * 8;
    const u16* Bp = ot + ((size_t)b * NN + n0 + l15) * CC + quad * 8;
    f32x4 acc[4] = {};
    #pragma unroll
    for (int kk = 0; kk < 8; ++kk) {
        b16x8 af = ldfrag(A + kk * 32);
        #pragma unroll
        for (int nt = 0; nt < 4; ++nt) {
            b16x8 bf = ldfrag(Bp + (size_t)nt * 16 * CC + kk * 32);
            acc[nt] = __builtin_amdgcn_mfma_f32_16x16x32_bf16(af, bf, acc[nt], 0, 0, 0);
        }
    }
    int o_base = o0 + w * 16 + quad * 4;
    #pragma unroll
    for (int nt = 0; nt < 4; ++nt) {
        int n = n0 + nt * 16 + l15;
        #pragma unroll
        for (int r = 0; r < 4; ++r) {
            int o = o_base + r;
            size_t idx = ((size_t)(b * CC + o)) * NN + n;
            out[idx] = acc[nt][r] + b_proj[o] + x[idx];
        }
    }
}

extern "C" void kernel_launch(void* const* d_in, const int* in_sizes, int n_in,
                              void* d_out, int out_size, void* d_ws, size_t ws_size,
                              hipStream_t stream) {
    const float* x      = (const float*)d_in[0];
    const float* gamma  = (const float*)d_in[1];
    const float* beta   = (const float*)d_in[2];
    const float* w_qkv  = (const float*)d_in[3];
    const float* w_proj = (const float*)d_in[4];
    const float* b_proj = (const float*)d_in[5];
    float* out = (float*)d_out;

    char* p = (char*)d_ws;
    float* stats = (float*)p; p += 256;
    float* biasq = (float*)p; p += (size_t)BB * 768 * sizeof(float);
    u16* wq_bf = (u16*)p; p += (size_t)BB * 768 * CC * 2;
    u16* wp_bf = (u16*)p; p += (size_t)CC * CC * 2;
    u16* xt = (u16*)p; p += (size_t)BB * NN * CC * 2;
    u16* qt = (u16*)p; p += (size_t)BB * NN * CC * 2;
    u16* kt = (u16*)p; p += (size_t)BB * NN * CC * 2;
    u16* vv = (u16*)p; p += (size_t)BB * NN * CC * 2;
    u16* ot = (u16*)p; p += (size_t)BB * NN * CC * 2;
    u16* po = (u16*)p; p += (size_t)SPLITS * BB * NN * CC * 2;
    float* lp = (float*)p; p += (size_t)SPLITS * BB * NN * sizeof(float);
    (void)ws_size; (void)in_sizes; (void)n_in; (void)out_size;

    gn_stats<<<BB * GG, 256, 0, stream>>>(x, stats);
    fold_w<<<dim3(768, BB), 256, 0, stream>>>(w_qkv, w_proj, gamma, beta, stats, wq_bf, biasq, wp_bf);
    transpose_x<<<dim3(NN / 64, CC / 64, BB), 256, 0, stream>>>(x, xt);
    qkv_gemm<<<dim3(NN / 64, 12, BB), 256, 0, stream>>>(wq_bf, biasq, xt, qt, kt, vv);
    flash<<<dim3(NN / 64, SPLITS, BB), 256, 0, stream>>>(qt, kt, vv, po, lp);
    combine<<<(BB * NN * CC / 8) / 256, 256, 0, stream>>>(po, lp, ot);
    proj<<<dim3(NN / 64, CC / 64, BB), 256, 0, stream>>>(wp_bf, b_proj, ot, x, out);
}

// Round 3
// 457.533 us; speedup vs baseline: 2.3830x; 1.5807x over previous
//
#include <hip/hip_runtime.h>

#define BB 4
#define CC 256
#define NN 4096
#define GG 8
#define SPLITS 8
#define KVPER (NN / SPLITS)

typedef unsigned short u16;
typedef unsigned int u32;
typedef __bf16 b16x8 __attribute__((ext_vector_type(8)));
typedef float f32x4 __attribute__((ext_vector_type(4)));
typedef u32 u32x4 __attribute__((ext_vector_type(4)));
typedef u16 u16x4 __attribute__((ext_vector_type(4)));

// Q pre-scale: C^-0.5 * log2(e) so softmax runs in exp2 domain
#define QSCALE 0.09016844005556021f
#define FMAX 16.0f

// fragment-major chunk: 512 u16 elems = 16 rows x 32 cols in MFMA lane order.
// elem(row, col32) = (quad(col32>>3)*16 + (row&15))*8 + (col32&7)
// A-read gives A[m=row][k=col]; B-read gives B[k=col][n=row].

__device__ __forceinline__ u16 f2bf(float f) {
    u32 u = __builtin_bit_cast(u32, f);
    u = (u + 0x7FFFu + ((u >> 16) & 1u)) >> 16;
    return (u16)u;
}

__device__ __forceinline__ float bf2f(u16 h) {
    return __builtin_bit_cast(float, (u32)h << 16);
}

__device__ __forceinline__ b16x8 ldfrag(const u16* p) {
    u32x4 v = *reinterpret_cast<const u32x4*>(p);
    return __builtin_bit_cast(b16x8, v);
}

// ---------------- 1. GroupNorm stats: one block per (b,g) ----------------
__global__ void gn_stats(const float* __restrict__ x, float* __restrict__ stats) {
    int bg = blockIdx.x;
    const float4* p4 = (const float4*)(x + (size_t)bg * (CC / GG) * NN);
    const int total4 = (CC / GG) * NN / 4;
    float s = 0.f, ss = 0.f;
    for (int i = threadIdx.x; i < total4; i += 256) {
        float4 v = p4[i];
        s  += v.x + v.y + v.z + v.w;
        ss += v.x * v.x + v.y * v.y + v.z * v.z + v.w * v.w;
    }
    #pragma unroll
    for (int off = 32; off; off >>= 1) {
        s  += __shfl_down(s, off, 64);
        ss += __shfl_down(ss, off, 64);
    }
    __shared__ float rs[4], rss[4];
    int wid = threadIdx.x >> 6;
    if ((threadIdx.x & 63) == 0) { rs[wid] = s; rss[wid] = ss; }
    __syncthreads();
    if (threadIdx.x == 0) {
        s  = rs[0] + rs[1] + rs[2] + rs[3];
        ss = rss[0] + rss[1] + rss[2] + rss[3];
        const float inv = 1.f / ((CC / GG) * NN);
        float mu = s * inv;
        float var = ss * inv - mu * mu;
        stats[bg * 2]     = mu;
        stats[bg * 2 + 1] = rsqrtf(var + 1e-5f);
    }
}

// ------- 2. Fold GN into QKV weights (frag-major) + frag-major w_proj -------
__global__ void fold_w(const float* __restrict__ w_qkv, const float* __restrict__ w_proj,
                       const float* __restrict__ gamma, const float* __restrict__ beta,
                       const float* __restrict__ stats,
                       u16* __restrict__ wqf, float* __restrict__ biasq,
                       u16* __restrict__ wpf) {
    int o = blockIdx.x;        // 0..767
    int b = blockIdx.y;        // 0..3
    int c = threadIdx.x;       // 0..255
    int g = c >> 5;
    float mu   = stats[(b * GG + g) * 2];
    float rstd = stats[(b * GG + g) * 2 + 1];
    float a  = gamma[c] * rstd;
    float bb = beta[c] - mu * a;
    float w = w_qkv[o * CC + c];
    size_t fe = ((size_t)((o >> 4) * 8 + (c >> 5)) * 64 + ((c & 31) >> 3) * 16 + (o & 15)) * 8 + (c & 7);
    wqf[(size_t)b * 768 * CC + fe] = f2bf(w * a);
    float part = w * bb;
    #pragma unroll
    for (int off = 32; off; off >>= 1) part += __shfl_down(part, off, 64);
    __shared__ float red[4];
    if ((threadIdx.x & 63) == 0) red[threadIdx.x >> 6] = part;
    __syncthreads();
    if (threadIdx.x == 0) biasq[b * 768 + o] = red[0] + red[1] + red[2] + red[3];
    if (b == 0 && o < CC) {
        float wp = w_proj[o * CC + c];
        wpf[fe] = f2bf(wp);   // same fe formula, o<256 region
    }
}

// ---------------- 3. x [B][C][N] fp32 -> xt_frag [B] frag16(N rows, C cols) ----------------
__global__ void transpose_x(const float* __restrict__ x, u16* __restrict__ xtf) {
    __shared__ float tile[64][65];
    int n0 = blockIdx.x * 64, c0 = blockIdx.y * 64, b = blockIdx.z;
    int t = threadIdx.x;
    int col = t & 63, r0 = t >> 6;
    const float* xp = x + (size_t)b * CC * NN;
    #pragma unroll
    for (int i = 0; i < 16; ++i) {
        int row = i * 4 + r0;
        tile[row][col] = xp[(size_t)(c0 + row) * NN + n0 + col];
    }
    __syncthreads();
    int nl = t >> 2;               // local n 0..63
    int cbq = t & 3;               // c block-of-16
    int l15 = nl & 15;
    int ntile = (n0 >> 4) + (nl >> 4);
    int kk = (c0 >> 5) + (cbq >> 1);
    u16* ob = xtf + (size_t)b * NN * CC;
    #pragma unroll
    for (int g = 0; g < 4; ++g) {
        int quad = (cbq & 1) * 2 + (g >> 1);
        int j0 = (g & 1) * 4;
        u16x4 v;
        v.x = f2bf(tile[cbq * 16 + g * 4 + 0][nl]);
        v.y = f2bf(tile[cbq * 16 + g * 4 + 1][nl]);
        v.z = f2bf(tile[cbq * 16 + g * 4 + 2][nl]);
        v.w = f2bf(tile[cbq * 16 + g * 4 + 3][nl]);
        *reinterpret_cast<u16x4*>(ob + ((size_t)(ntile * 8 + kk) * 64 + quad * 16 + l15) * 8 + j0) = v;
    }
}

// ------- 4. QKV GEMM -> qt_frag, kt_frag (N rows x C cols), v_frag (C rows x N cols) -------
__global__ void __launch_bounds__(256) qkv_gemm(const u16* __restrict__ wqf,
                                                const float* __restrict__ biasq,
                                                const u16* __restrict__ xtf,
                                                u16* __restrict__ qtf, u16* __restrict__ ktf,
                                                u16* __restrict__ vvf) {
    int b = blockIdx.z;
    int o0 = blockIdx.y * 64;
    int n0 = blockIdx.x * 64;
    int lane = threadIdx.x & 63, w = threadIdx.x >> 6;
    int l15 = lane & 15, quad = lane >> 4;
    const u16* A  = wqf + (size_t)b * 768 * CC;
    const u16* Bp = xtf + (size_t)b * NN * CC;
    int otile = (o0 >> 4) + w;
    f32x4 acc[4] = {};
    #pragma unroll
    for (int kk = 0; kk < 8; ++kk) {
        b16x8 af = ldfrag(A + (size_t)(otile * 8 + kk) * 512 + lane * 8);
        #pragma unroll
        for (int nt = 0; nt < 4; ++nt) {
            b16x8 bf = ldfrag(Bp + (size_t)(((n0 >> 4) + nt) * 8 + kk) * 512 + lane * 8);
            acc[nt] = __builtin_amdgcn_mfma_f32_16x16x32_bf16(af, bf, acc[nt], 0, 0, 0);
        }
    }
    int o_base = o0 + w * 16 + quad * 4;           // global o of r=0
    float bias[4];
    #pragma unroll
    for (int r = 0; r < 4; ++r) bias[r] = biasq[b * 768 + o_base + r];

    if (o0 < 512) {
        // Q or K: frag16 rows = token n, cols = c (= o or o-256)
        int oloc = (o0 < 256) ? o0 : (o0 - 256);
        int kk = (oloc >> 5) + (w >> 1);
        int q_t = (w & 1) * 2 + (quad >> 1);
        int j0 = (quad & 1) * 4;
        u16* dst = ((o0 < 256) ? qtf : ktf) + (size_t)b * NN * CC;
        float sc = (o0 < 256) ? QSCALE : 1.0f;
        #pragma unroll
        for (int nt = 0; nt < 4; ++nt) {
            int n = n0 + nt * 16 + l15;
            int ntile = n >> 4;
            u16x4 pk;
            pk.x = f2bf((acc[nt][0] + bias[0]) * sc);
            pk.y = f2bf((acc[nt][1] + bias[1]) * sc);
            pk.z = f2bf((acc[nt][2] + bias[2]) * sc);
            pk.w = f2bf((acc[nt][3] + bias[3]) * sc);
            *reinterpret_cast<u16x4*>(dst + ((size_t)(ntile * 8 + kk) * 64 + q_t * 16 + l15) * 8 + j0) = pk;
        }
    } else {
        // V: frag16 rows = c, cols = token n
        int ctile = ((o0 - 512) + w * 16) >> 4;
        u16* dst = vvf + (size_t)b * NN * CC;
        int jv = l15 & 7;
        #pragma unroll
        for (int nt = 0; nt < 4; ++nt) {
            int kkv = (n0 >> 5) + (nt >> 1);
            int q_v = (nt * 2 + (l15 >> 3)) & 3;
            size_t cb = (size_t)(ctile * (NN / 32) + kkv) * 512;
            #pragma unroll
            for (int r = 0; r < 4; ++r)
                dst[cb + (size_t)(q_v * 16 + quad * 4 + r) * 8 + jv] = f2bf(acc[nt][r] + bias[r]);
        }
    }
}

// ---------------- 5. Flash attention, split-KV, fixed-max softmax ----------------
__global__ void __launch_bounds__(256, 4) flash(const u16* __restrict__ qtf,
                                                const u16* __restrict__ ktf,
                                                const u16* __restrict__ vvf,
                                                u16* __restrict__ po,
                                                float* __restrict__ lp) {
    int b = blockIdx.z;
    int sp = blockIdx.y;
    int n0 = blockIdx.x * 64;
    int lane = threadIdx.x & 63, w = threadIdx.x >> 6;
    int l15 = lane & 15, quad = lane >> 4;
    __shared__ u16 plds[4][16 * 80];
    u16* pl = &plds[w][0];

    const u16* qb = qtf + (size_t)b * NN * CC;
    const u16* kb = ktf + (size_t)b * NN * CC;
    const u16* vb = vvf + (size_t)b * NN * CC;

    int ntile = (n0 >> 4) + w;
    b16x8 aq[8];
    #pragma unroll
    for (int kk = 0; kk < 8; ++kk)
        aq[kk] = ldfrag(qb + (size_t)(ntile * 8 + kk) * 512 + lane * 8);

    f32x4 acco[16] = {};
    float l_r[4] = {0.f, 0.f, 0.f, 0.f};

    const int m_beg = sp * KVPER;
    for (int m0 = m_beg; m0 < m_beg + KVPER; m0 += 64) {
        f32x4 accs[4] = {};
        int mt0 = m0 >> 4;
        #pragma unroll
        for (int kk = 0; kk < 8; ++kk) {
            #pragma unroll
            for (int mt = 0; mt < 4; ++mt) {
                b16x8 bk = ldfrag(kb + (size_t)((mt0 + mt) * 8 + kk) * 512 + lane * 8);
                accs[mt] = __builtin_amdgcn_mfma_f32_16x16x32_bf16(aq[kk], bk, accs[mt], 0, 0, 0);
            }
        }
        #pragma unroll
        for (int mt = 0; mt < 4; ++mt) {
            #pragma unroll
            for (int r = 0; r < 4; ++r) accs[mt][r] = exp2f(accs[mt][r] - FMAX);
        }
        #pragma unroll
        for (int r = 0; r < 4; ++r)
            l_r[r] += accs[0][r] + accs[1][r] + accs[2][r] + accs[3][r];
        #pragma unroll
        for (int mt = 0; mt < 4; ++mt) {
            #pragma unroll
            for (int r = 0; r < 4; ++r)
                pl[(quad * 4 + r) * 80 + mt * 16 + l15] = f2bf(accs[mt][r]);
        }
        __asm__ volatile("s_waitcnt lgkmcnt(0)" ::: "memory");
        int kv0 = m0 >> 5;
        #pragma unroll
        for (int ks = 0; ks < 2; ++ks) {
            b16x8 ap = ldfrag(pl + l15 * 80 + ks * 32 + quad * 8);
            #pragma unroll
            for (int ct = 0; ct < 16; ++ct) {
                b16x8 bv = ldfrag(vb + (size_t)(ct * (NN / 32) + kv0 + ks) * 512 + lane * 8);
                acco[ct] = __builtin_amdgcn_mfma_f32_16x16x32_bf16(ap, bv, acco[ct], 0, 0, 0);
            }
        }
    }
    #pragma unroll
    for (int off = 1; off < 16; off <<= 1) {
        #pragma unroll
        for (int r = 0; r < 4; ++r) l_r[r] += __shfl_xor(l_r[r], off, 64);
    }
    size_t obase = ((size_t)(sp * BB + b) * NN + n0 + w * 16);
    u16* Op = po + obase * CC;
    #pragma unroll
    for (int ct = 0; ct < 16; ++ct) {
        #pragma unroll
        for (int r = 0; r < 4; ++r)
            Op[(size_t)(quad * 4 + r) * CC + ct * 16 + l15] = f2bf(acco[ct][r]);
    }
    if (l15 == 0) {
        #pragma unroll
        for (int r = 0; r < 4; ++r) lp[obase + quad * 4 + r] = l_r[r];
    }
}

// ---------------- 5b. combine -> ot_frag ----------------
__global__ void __launch_bounds__(256) combine(const u16* __restrict__ po,
                                               const float* __restrict__ lp,
                                               u16* __restrict__ otf) {
    int idx = blockIdx.x * 256 + threadIdx.x;
    int bn = idx >> 5;
    int c8 = (idx & 31) * 8;
    int b = bn >> 12;
    int n = bn & (NN - 1);
    float acc[8] = {};
    float lsum = 0.f;
    #pragma unroll
    for (int s = 0; s < SPLITS; ++s) {
        lsum += lp[(size_t)s * BB * NN + bn];
        u32x4 v = *reinterpret_cast<const u32x4*>(po + (((size_t)s * BB * NN + bn) * CC + c8));
        const u16* pv = reinterpret_cast<const u16*>(&v);
        #pragma unroll
        for (int j = 0; j < 8; ++j) acc[j] += bf2f(pv[j]);
    }
    float inv = 1.f / lsum;
    u16 outv[8];
    #pragma unroll
    for (int j = 0; j < 8; ++j) outv[j] = f2bf(acc[j] * inv);
    int kk = c8 >> 5, quad = (c8 >> 3) & 3;
    *reinterpret_cast<u32x4*>(otf + (size_t)b * NN * CC +
        ((size_t)((n >> 4) * 8 + kk) * 64 + quad * 16 + (n & 15)) * 8) =
        *reinterpret_cast<const u32x4*>(outv);
}

// ------- 6. proj GEMM + bias + residual ----------------
__global__ void __launch_bounds__(256) proj(const u16* __restrict__ wpf,
                                            const float* __restrict__ b_proj,
                                            const u16* __restrict__ otf,
                                            const float* __restrict__ x,
                                            float* __restrict__ out) {
    int b = blockIdx.z, o0 = blockIdx.y * 64, n0 = blockIdx.x * 64;
    int lane = threadIdx.x & 63, w = threadIdx.x >> 6;
    int l15 = lane & 15, quad = lane >> 4;
    const u16* Bp = otf + (size_t)b * NN * CC;
    int otile = (o0 >> 4) + w;
    f32x4 acc[4] = {};
    #pragma unroll
    for (int kk = 0; kk < 8; ++kk) {
        b16x8 af = ldfrag(wpf + (size_t)(otile * 8 + kk) * 512 + lane * 8);
        #pragma unroll
        for (int nt = 0; nt < 4; ++nt) {
            b16x8 bf = ldfrag(Bp + (size_t)(((n0 >> 4) + nt) * 8 + kk) * 512 + lane * 8);
            acc[nt] = __builtin_amdgcn_mfma_f32_16x16x32_bf16(af, bf, acc[nt], 0, 0, 0);
        }
    }
    int o_base = o0 + w * 16 + quad * 4;
    #pragma unroll
    for (int nt = 0; nt < 4; ++nt) {
        int n = n0 + nt * 16 + l15;
        #pragma unroll
        for (int r = 0; r < 4; ++r) {
            int o = o_base + r;
            size_t idx = ((size_t)(b * CC + o)) * NN + n;
            out[idx] = acc[nt][r] + b_proj[o] + x[idx];
        }
    }
}

extern "C" void kernel_launch(void* const* d_in, const int* in_sizes, int n_in,
                              void* d_out, int out_size, void* d_ws, size_t ws_size,
                              hipStream_t stream) {
    const float* x      = (const float*)d_in[0];
    const float* gamma  = (const float*)d_in[1];
    const float* beta   = (const float*)d_in[2];
    const float* w_qkv  = (const float*)d_in[3];
    const float* w_proj = (const float*)d_in[4];
    const float* b_proj = (const float*)d_in[5];
    float* out = (float*)d_out;

    char* p = (char*)d_ws;
    float* stats = (float*)p; p += 256;
    float* biasq = (float*)p; p += (size_t)BB * 768 * sizeof(float);
    u16* wqf = (u16*)p; p += (size_t)BB * 768 * CC * 2;
    u16* wpf = (u16*)p; p += (size_t)CC * CC * 2;
    u16* xtf = (u16*)p; p += (size_t)BB * NN * CC * 2;
    u16* qtf = (u16*)p; p += (size_t)BB * NN * CC * 2;
    u16* ktf = (u16*)p; p += (size_t)BB * NN * CC * 2;
    u16* vvf = (u16*)p; p += (size_t)BB * NN * CC * 2;
    u16* otf = (u16*)p; p += (size_t)BB * NN * CC * 2;
    u16* po = (u16*)p; p += (size_t)SPLITS * BB * NN * CC * 2;
    float* lp = (float*)p; p += (size_t)SPLITS * BB * NN * sizeof(float);
    (void)ws_size; (void)in_sizes; (void)n_in; (void)out_size;

    gn_stats<<<BB * GG, 256, 0, stream>>>(x, stats);
    fold_w<<<dim3(768, BB), 256, 0, stream>>>(w_qkv, w_proj, gamma, beta, stats, wqf, biasq, wpf);
    transpose_x<<<dim3(NN / 64, CC / 64, BB), 256, 0, stream>>>(x, xtf);
    qkv_gemm<<<dim3(NN / 64, 12, BB), 256, 0, stream>>>(wqf, biasq, xtf, qtf, ktf, vvf);
    flash<<<dim3(NN / 64, SPLITS, BB), 256, 0, stream>>>(qtf, ktf, vvf, po, lp);
    combine<<<(BB * NN * CC / 8) / 256, 256, 0, stream>>>(po, lp, otf);
    proj<<<dim3(NN / 64, CC / 64, BB), 256, 0, stream>>>(wpf, b_proj, otf, x, out);
}

// Round 4
// 225.395 us; speedup vs baseline: 4.8372x; 2.0299x over previous
//
#include <hip/hip_runtime.h>

#define BB 4
#define CC 256
#define NN 4096
#define GG 8
#define SPLITS 4
#define MBLK 128
#define TKV 32
#define ITERS (NN / SPLITS / TKV)

typedef unsigned short u16;
typedef unsigned int u32;
typedef __bf16 b16x8 __attribute__((ext_vector_type(8)));
typedef float f32x4 __attribute__((ext_vector_type(4)));
typedef u32 u32x4 __attribute__((ext_vector_type(4)));
typedef u16 u16x4 __attribute__((ext_vector_type(4)));

// Q pre-scale: C^-0.5 * log2(e) so softmax runs in exp2 domain
#define QSCALE 0.09016844005556021f
#define FMAX 16.0f

// fragment-major chunk: 512 u16 elems = 16 rows x 32 cols in MFMA lane order.
// elem(row, col32) = (quad(col32>>3)*16 + (row&15))*8 + (col32&7)
// A-read gives A[m=row][k=col]; B-read gives B[k=col][n=row].

__device__ __forceinline__ u16 f2bf(float f) {
    u32 u = __builtin_bit_cast(u32, f);
    u = (u + 0x7FFFu + ((u >> 16) & 1u)) >> 16;
    return (u16)u;
}

__device__ __forceinline__ float bf2f(u16 h) {
    return __builtin_bit_cast(float, (u32)h << 16);
}

__device__ __forceinline__ b16x8 ldfrag(const u16* p) {
    u32x4 v = *reinterpret_cast<const u32x4*>(p);
    return __builtin_bit_cast(b16x8, v);
}

typedef __attribute__((address_space(1))) const unsigned int* gas_p;
typedef __attribute__((address_space(3))) unsigned int* las_p;

// async global->LDS: lane i's 16B at g+lane*16 lands at lds_base + lane*16
__device__ __forceinline__ void g2l(const u16* g, u16* l) {
    __builtin_amdgcn_global_load_lds((gas_p)g, (las_p)l, 16, 0, 0);
}

// ------- 2. Fold GN into QKV weights (frag-major) + frag-major w_proj -------
__global__ void fold_w(const float* __restrict__ w_qkv, const float* __restrict__ w_proj,
                       const float* __restrict__ gamma, const float* __restrict__ beta,
                       const float* __restrict__ stats,
                       u16* __restrict__ wqf, float* __restrict__ biasq,
                       u16* __restrict__ wpf) {
    int o = blockIdx.x;        // 0..767
    int b = blockIdx.y;        // 0..3
    int c = threadIdx.x;       // 0..255
    int g = c >> 5;
    float mu   = stats[(b * GG + g) * 2];
    float rstd = stats[(b * GG + g) * 2 + 1];
    float a  = gamma[c] * rstd;
    float bb = beta[c] - mu * a;
    float w = w_qkv[o * CC + c];
    size_t fe = ((size_t)((o >> 4) * 8 + (c >> 5)) * 64 + ((c & 31) >> 3) * 16 + (o & 15)) * 8 + (c & 7);
    wqf[(size_t)b * 768 * CC + fe] = f2bf(w * a);
    float part = w * bb;
    #pragma unroll
    for (int off = 32; off; off >>= 1) part += __shfl_down(part, off, 64);
    __shared__ float red[4];
    if ((threadIdx.x & 63) == 0) red[threadIdx.x >> 6] = part;
    __syncthreads();
    if (threadIdx.x == 0) biasq[b * 768 + o] = red[0] + red[1] + red[2] + red[3];
    if (b == 0 && o < CC) {
        float wp = w_proj[o * CC + c];
        wpf[fe] = f2bf(wp);
    }
}

// ---- 3. x [B][C][N] fp32 -> xt_frag; fused GroupNorm partial sums ----
__global__ void transpose_x(const float* __restrict__ x, u16* __restrict__ xtf,
                            float* __restrict__ gsum) {
    __shared__ float tile[64][65];
    __shared__ float red[4][4];
    int n0 = blockIdx.x * 64, c0 = blockIdx.y * 64, b = blockIdx.z;
    int t = threadIdx.x;
    int col = t & 63, r0 = t >> 6;
    const float* xp = x + (size_t)b * CC * NN;
    float s0 = 0.f, ss0 = 0.f, s1 = 0.f, ss1 = 0.f;
    #pragma unroll
    for (int i = 0; i < 16; ++i) {
        int row = i * 4 + r0;
        float v = xp[(size_t)(c0 + row) * NN + n0 + col];
        tile[row][col] = v;
        if (i < 8) { s0 += v; ss0 += v * v; } else { s1 += v; ss1 += v * v; }
    }
    #pragma unroll
    for (int off = 32; off; off >>= 1) {
        s0 += __shfl_down(s0, off, 64); ss0 += __shfl_down(ss0, off, 64);
        s1 += __shfl_down(s1, off, 64); ss1 += __shfl_down(ss1, off, 64);
    }
    int wid = t >> 6;
    if ((t & 63) == 0) { red[wid][0] = s0; red[wid][1] = ss0; red[wid][2] = s1; red[wid][3] = ss1; }
    __syncthreads();
    if (t < 2) {
        float s  = red[0][t * 2] + red[1][t * 2] + red[2][t * 2] + red[3][t * 2];
        float ss = red[0][t * 2 + 1] + red[1][t * 2 + 1] + red[2][t * 2 + 1] + red[3][t * 2 + 1];
        int g = (c0 >> 5) + t;
        atomicAdd(&gsum[(b * GG + g) * 2], s);
        atomicAdd(&gsum[(b * GG + g) * 2 + 1], ss);
    }
    int nl = t >> 2;
    int cbq = t & 3;
    int l15 = nl & 15;
    int ntile = (n0 >> 4) + (nl >> 4);
    int kk = (c0 >> 5) + (cbq >> 1);
    u16* ob = xtf + (size_t)b * NN * CC;
    #pragma unroll
    for (int g = 0; g < 4; ++g) {
        int quad = (cbq & 1) * 2 + (g >> 1);
        int j0 = (g & 1) * 4;
        u16x4 v;
        v.x = f2bf(tile[cbq * 16 + g * 4 + 0][nl]);
        v.y = f2bf(tile[cbq * 16 + g * 4 + 1][nl]);
        v.z = f2bf(tile[cbq * 16 + g * 4 + 2][nl]);
        v.w = f2bf(tile[cbq * 16 + g * 4 + 3][nl]);
        *reinterpret_cast<u16x4*>(ob + ((size_t)(ntile * 8 + kk) * 64 + quad * 16 + l15) * 8 + j0) = v;
    }
}

// ---------------- 3b. finalize GN stats ----------------
__global__ void gn_finalize(const float* __restrict__ gsum, float* __restrict__ stats) {
    int i = threadIdx.x;
    if (i < BB * GG) {
        float s = gsum[i * 2], ss = gsum[i * 2 + 1];
        const float inv = 1.f / ((CC / GG) * NN);
        float mu = s * inv;
        float var = ss * inv - mu * mu;
        stats[i * 2] = mu;
        stats[i * 2 + 1] = rsqrtf(var + 1e-5f);
    }
}

// ------- 4. QKV GEMM -> qt_frag, kt_frag (N rows x C cols), v_frag (C rows x N cols) -------
__global__ void __launch_bounds__(256) qkv_gemm(const u16* __restrict__ wqf,
                                                const float* __restrict__ biasq,
                                                const u16* __restrict__ xtf,
                                                u16* __restrict__ qtf, u16* __restrict__ ktf,
                                                u16* __restrict__ vvf) {
    int b = blockIdx.z;
    int o0 = blockIdx.y * 64;
    int n0 = blockIdx.x * 64;
    int lane = threadIdx.x & 63, w = threadIdx.x >> 6;
    int l15 = lane & 15, quad = lane >> 4;
    const u16* A  = wqf + (size_t)b * 768 * CC;
    const u16* Bp = xtf + (size_t)b * NN * CC;
    int otile = (o0 >> 4) + w;
    f32x4 acc[4] = {};
    #pragma unroll
    for (int kk = 0; kk < 8; ++kk) {
        b16x8 af = ldfrag(A + (size_t)(otile * 8 + kk) * 512 + lane * 8);
        #pragma unroll
        for (int nt = 0; nt < 4; ++nt) {
            b16x8 bf = ldfrag(Bp + (size_t)(((n0 >> 4) + nt) * 8 + kk) * 512 + lane * 8);
            acc[nt] = __builtin_amdgcn_mfma_f32_16x16x32_bf16(af, bf, acc[nt], 0, 0, 0);
        }
    }
    int o_base = o0 + w * 16 + quad * 4;
    float bias[4];
    #pragma unroll
    for (int r = 0; r < 4; ++r) bias[r] = biasq[b * 768 + o_base + r];

    if (o0 < 512) {
        int oloc = (o0 < 256) ? o0 : (o0 - 256);
        int kk = (oloc >> 5) + (w >> 1);
        int q_t = (w & 1) * 2 + (quad >> 1);
        int j0 = (quad & 1) * 4;
        u16* dst = ((o0 < 256) ? qtf : ktf) + (size_t)b * NN * CC;
        float sc = (o0 < 256) ? QSCALE : 1.0f;
        #pragma unroll
        for (int nt = 0; nt < 4; ++nt) {
            int n = n0 + nt * 16 + l15;
            int ntile = n >> 4;
            u16x4 pk;
            pk.x = f2bf((acc[nt][0] + bias[0]) * sc);
            pk.y = f2bf((acc[nt][1] + bias[1]) * sc);
            pk.z = f2bf((acc[nt][2] + bias[2]) * sc);
            pk.w = f2bf((acc[nt][3] + bias[3]) * sc);
            *reinterpret_cast<u16x4*>(dst + ((size_t)(ntile * 8 + kk) * 64 + q_t * 16 + l15) * 8 + j0) = pk;
        }
    } else {
        int ctile = ((o0 - 512) + w * 16) >> 4;
        u16* dst = vvf + (size_t)b * NN * CC;
        int jv = l15 & 7;
        #pragma unroll
        for (int nt = 0; nt < 4; ++nt) {
            int kkv = (n0 >> 5) + (nt >> 1);
            int q_v = (nt * 2 + (l15 >> 3)) & 3;
            size_t cb = (size_t)(ctile * (NN / 32) + kkv) * 512;
            #pragma unroll
            for (int r = 0; r < 4; ++r)
                dst[cb + (size_t)(q_v * 16 + quad * 4 + r) * 8 + jv] = f2bf(acc[nt][r] + bias[r]);
        }
    }
}

// ---------------- 5. Flash: M_block=128, LDS-staged K/V, double-buffered ----------------
__global__ void __launch_bounds__(256, 2) flash(const u16* __restrict__ qtf,
                                                const u16* __restrict__ ktf,
                                                const u16* __restrict__ vvf,
                                                u16* __restrict__ po,
                                                float* __restrict__ lp) {
    __shared__ u16 kbuf[2][16 * 512];      // 2 x 16KB
    __shared__ u16 vbuf[2][16 * 512];      // 2 x 16KB
    __shared__ u16 pbuf[4][32 * 36];       // per-wave P, stride 36
    int b = blockIdx.z, sp = blockIdx.y;
    int n0 = blockIdx.x * MBLK;
    int lane = threadIdx.x & 63, w = threadIdx.x >> 6;
    int l15 = lane & 15, quad = lane >> 4;
    const u16* qb = qtf + (size_t)b * NN * CC;
    const u16* kb = ktf + (size_t)b * NN * CC;
    const u16* vb = vvf + (size_t)b * NN * CC;
    u16* pw = &pbuf[w][0];

    // Q: 32 rows per wave, held in registers
    b16x8 aq[2][8];
    int nt0 = (n0 + w * 32) >> 4;
    #pragma unroll
    for (int a = 0; a < 2; ++a)
        #pragma unroll
        for (int kk = 0; kk < 8; ++kk)
            aq[a][kk] = ldfrag(qb + (size_t)((nt0 + a) * 8 + kk) * 512 + lane * 8);

    f32x4 acco[2][16] = {};
    float l_r[2][4] = {};

    const int m_beg = sp * (NN / SPLITS);

    // stage KV tile (32 tokens): 32 chunks of 1KB, wave w does chunks w*8..w*8+7
    auto stage = [&](int buf, int m0) {
        int mt0 = m0 >> 4, kv32 = m0 >> 5;
        #pragma unroll
        for (int j = 0; j < 8; ++j) {
            int c = w * 8 + j;
            const u16* g;
            u16* l;
            if (c < 16) {
                g = kb + (size_t)((mt0 + (c >> 3)) * 8 + (c & 7)) * 512;
                l = &kbuf[buf][c * 512];
            } else {
                int ct = c - 16;
                g = vb + (size_t)(ct * (NN / 32) + kv32) * 512;
                l = &vbuf[buf][ct * 512];
            }
            g2l(g + lane * 8, l);
        }
    };

    stage(0, m_beg);
    __syncthreads();
    for (int it = 0; it < ITERS; ++it) {
        int cur = it & 1;
        if (it + 1 < ITERS) stage(cur ^ 1, m_beg + (it + 1) * TKV);
        const u16* kc = &kbuf[cur][0];
        const u16* vc = &vbuf[cur][0];
        // QK: S tile 32x32 per wave pair-of-mtiles
        f32x4 accs[2][2] = {};
        #pragma unroll
        for (int kk = 0; kk < 8; ++kk) {
            #pragma unroll
            for (int m = 0; m < 2; ++m) {
                b16x8 bk = ldfrag(kc + (size_t)(m * 8 + kk) * 512 + lane * 8);
                accs[0][m] = __builtin_amdgcn_mfma_f32_16x16x32_bf16(aq[0][kk], bk, accs[0][m], 0, 0, 0);
                accs[1][m] = __builtin_amdgcn_mfma_f32_16x16x32_bf16(aq[1][kk], bk, accs[1][m], 0, 0, 0);
            }
        }
        // exp2, l accumulation, P -> LDS (A-frag layout)
        #pragma unroll
        for (int a = 0; a < 2; ++a) {
            #pragma unroll
            for (int m = 0; m < 2; ++m) {
                #pragma unroll
                for (int r = 0; r < 4; ++r) {
                    float e = exp2f(accs[a][m][r] - FMAX);
                    l_r[a][r] += e;
                    pw[(a * 16 + quad * 4 + r) * 36 + m * 16 + l15] = f2bf(e);
                }
            }
        }
        asm volatile("s_waitcnt lgkmcnt(0)" ::: "memory");
        b16x8 ap[2];
        #pragma unroll
        for (int a = 0; a < 2; ++a)
            ap[a] = ldfrag(pw + (size_t)(a * 16 + l15) * 36 + quad * 8);
        #pragma unroll
        for (int ct = 0; ct < 16; ++ct) {
            b16x8 bv = ldfrag(vc + (size_t)ct * 512 + lane * 8);
            acco[0][ct] = __builtin_amdgcn_mfma_f32_16x16x32_bf16(ap[0], bv, acco[0][ct], 0, 0, 0);
            acco[1][ct] = __builtin_amdgcn_mfma_f32_16x16x32_bf16(ap[1], bv, acco[1][ct], 0, 0, 0);
        }
        __syncthreads();
    }
    // epilogue
    #pragma unroll
    for (int off = 1; off < 16; off <<= 1) {
        #pragma unroll
        for (int a = 0; a < 2; ++a)
            #pragma unroll
            for (int r = 0; r < 4; ++r)
                l_r[a][r] += __shfl_xor(l_r[a][r], off, 64);
    }
    #pragma unroll
    for (int a = 0; a < 2; ++a) {
        size_t obase = (size_t)(sp * BB + b) * NN + n0 + w * 32 + a * 16;
        u16* Op = po + obase * CC;
        #pragma unroll
        for (int ct = 0; ct < 16; ++ct) {
            #pragma unroll
            for (int r = 0; r < 4; ++r)
                Op[(size_t)(quad * 4 + r) * CC + ct * 16 + l15] = f2bf(acco[a][ct][r]);
        }
        if (l15 == 0) {
            #pragma unroll
            for (int r = 0; r < 4; ++r) lp[obase + quad * 4 + r] = l_r[a][r];
        }
    }
}

// ---------------- 5b. combine -> ot_frag ----------------
__global__ void __launch_bounds__(256) combine(const u16* __restrict__ po,
                                               const float* __restrict__ lp,
                                               u16* __restrict__ otf) {
    int idx = blockIdx.x * 256 + threadIdx.x;
    int bn = idx >> 5;
    int c8 = (idx & 31) * 8;
    int b = bn >> 12;
    int n = bn & (NN - 1);
    float acc[8] = {};
    float lsum = 0.f;
    #pragma unroll
    for (int s = 0; s < SPLITS; ++s) {
        lsum += lp[(size_t)s * BB * NN + bn];
        u32x4 v = *reinterpret_cast<const u32x4*>(po + (((size_t)s * BB * NN + bn) * CC + c8));
        const u16* pv = reinterpret_cast<const u16*>(&v);
        #pragma unroll
        for (int j = 0; j < 8; ++j) acc[j] += bf2f(pv[j]);
    }
    float inv = 1.f / lsum;
    u16 outv[8];
    #pragma unroll
    for (int j = 0; j < 8; ++j) outv[j] = f2bf(acc[j] * inv);
    int kk = c8 >> 5, quad = (c8 >> 3) & 3;
    *reinterpret_cast<u32x4*>(otf + (size_t)b * NN * CC +
        ((size_t)((n >> 4) * 8 + kk) * 64 + quad * 16 + (n & 15)) * 8) =
        *reinterpret_cast<const u32x4*>(outv);
}

// ------- 6. proj GEMM + bias + residual ----------------
__global__ void __launch_bounds__(256) proj(const u16* __restrict__ wpf,
                                            const float* __restrict__ b_proj,
                                            const u16* __restrict__ otf,
                                            const float* __restrict__ x,
                                            float* __restrict__ out) {
    int b = blockIdx.z, o0 = blockIdx.y * 64, n0 = blockIdx.x * 64;
    int lane = threadIdx.x & 63, w = threadIdx.x >> 6;
    int l15 = lane & 15, quad = lane >> 4;
    const u16* Bp = otf + (size_t)b * NN * CC;
    int otile = (o0 >> 4) + w;
    f32x4 acc[4] = {};
    #pragma unroll
    for (int kk = 0; kk < 8; ++kk) {
        b16x8 af = ldfrag(wpf + (size_t)(otile * 8 + kk) * 512 + lane * 8);
        #pragma unroll
        for (int nt = 0; nt < 4; ++nt) {
            b16x8 bf = ldfrag(Bp + (size_t)(((n0 >> 4) + nt) * 8 + kk) * 512 + lane * 8);
            acc[nt] = __builtin_amdgcn_mfma_f32_16x16x32_bf16(af, bf, acc[nt], 0, 0, 0);
        }
    }
    int o_base = o0 + w * 16 + quad * 4;
    #pragma unroll
    for (int nt = 0; nt < 4; ++nt) {
        int n = n0 + nt * 16 + l15;
        #pragma unroll
        for (int r = 0; r < 4; ++r) {
            int o = o_base + r;
            size_t idx = ((size_t)(b * CC + o)) * NN + n;
            out[idx] = acc[nt][r] + b_proj[o] + x[idx];
        }
    }
}

extern "C" void kernel_launch(void* const* d_in, const int* in_sizes, int n_in,
                              void* d_out, int out_size, void* d_ws, size_t ws_size,
                              hipStream_t stream) {
    const float* x      = (const float*)d_in[0];
    const float* gamma  = (const float*)d_in[1];
    const float* beta   = (const float*)d_in[2];
    const float* w_qkv  = (const float*)d_in[3];
    const float* w_proj = (const float*)d_in[4];
    const float* b_proj = (const float*)d_in[5];
    float* out = (float*)d_out;

    char* p = (char*)d_ws;
    float* stats = (float*)p; p += 256;
    float* gsum  = (float*)p; p += 256;
    float* biasq = (float*)p; p += (size_t)BB * 768 * sizeof(float);
    u16* wqf = (u16*)p; p += (size_t)BB * 768 * CC * 2;
    u16* wpf = (u16*)p; p += (size_t)CC * CC * 2;
    u16* xtf = (u16*)p; p += (size_t)BB * NN * CC * 2;
    u16* qtf = (u16*)p; p += (size_t)BB * NN * CC * 2;
    u16* ktf = (u16*)p; p += (size_t)BB * NN * CC * 2;
    u16* vvf = (u16*)p; p += (size_t)BB * NN * CC * 2;
    u16* otf = (u16*)p; p += (size_t)BB * NN * CC * 2;
    u16* po = (u16*)p; p += (size_t)SPLITS * BB * NN * CC * 2;
    float* lp = (float*)p; p += (size_t)SPLITS * BB * NN * sizeof(float);
    (void)ws_size; (void)in_sizes; (void)n_in; (void)out_size;

    hipMemsetAsync(gsum, 0, BB * GG * 2 * sizeof(float), stream);
    transpose_x<<<dim3(NN / 64, CC / 64, BB), 256, 0, stream>>>(x, xtf, gsum);
    gn_finalize<<<1, 64, 0, stream>>>(gsum, stats);
    fold_w<<<dim3(768, BB), 256, 0, stream>>>(w_qkv, w_proj, gamma, beta, stats, wqf, biasq, wpf);
    qkv_gemm<<<dim3(NN / 64, 12, BB), 256, 0, stream>>>(wqf, biasq, xtf, qtf, ktf, vvf);
    flash<<<dim3(NN / MBLK, SPLITS, BB), 256, 0, stream>>>(qtf, ktf, vvf, po, lp);
    combine<<<(BB * NN * CC / 8) / 256, 256, 0, stream>>>(po, lp, otf);
    proj<<<dim3(NN / 64, CC / 64, BB), 256, 0, stream>>>(wpf, b_proj, otf, x, out);
}